// Round 1
// baseline (290.860 us; speedup 1.0000x reference)
//
#include <hip/hip_runtime.h>
#include <hip/hip_bf16.h>

#define D_DIM 256
#define H_DIM 128
#define B_DIM 256
#define S_DIM 512
#define NTOK (B_DIM * S_DIM)
#define W1_LD 517

// workspace layout (floats)
#define WS_DIT 0
#define WS_E 256
#define WS_C0 512
#define WS_SCORE 1024
#define WS_ARAW (1024 + NTOK)

__device__ __forceinline__ float wave_sum(float v) {
#pragma unroll
  for (int off = 32; off > 0; off >>= 1) v += __shfl_xor(v, off, 64);
  return v;
}
__device__ __forceinline__ float wave_max(float v) {
#pragma unroll
  for (int off = 32; off > 0; off >>= 1) v = fmaxf(v, __shfl_xor(v, off, 64));
  return v;
}
__device__ __forceinline__ float block_sum(float v, float* scr) {
  v = wave_sum(v);
  int wid = threadIdx.x >> 6;
  __syncthreads();
  if ((threadIdx.x & 63) == 0) scr[wid] = v;
  __syncthreads();
  return scr[0] + scr[1] + scr[2] + scr[3];
}
__device__ __forceinline__ float block_max(float v, float* scr) {
  v = wave_max(v);
  int wid = threadIdx.x >> 6;
  __syncthreads();
  if ((threadIdx.x & 63) == 0) scr[wid] = v;
  __syncthreads();
  return fmaxf(fmaxf(scr[0], scr[1]), fmaxf(scr[2], scr[3]));
}

// ---------------------------------------------------------------------------
// Setup: per-d constants for the rearranged score
//   s = -0.5 * sum_d[(var + mu^2)*dit_d - 2*mu*e_d] + C0
//   dit = 1/tau2_1 - 1/tau2_0 ; e = mc1/tau2_1 - mc0/tau2_0
//   C0  = (lp1-lp0) - 0.5*sum_d[ mc1^2/tau2_1 - mc0^2/tau2_0 + lt1 - lt0 ]
// ---------------------------------------------------------------------------
__global__ void k_setup(const float* __restrict__ mu_c,
                        const float* __restrict__ log_tau2,
                        const float* __restrict__ log_prior,
                        float* __restrict__ wsc) {
  __shared__ float scr[4];
  int d = threadIdx.x;  // 256 threads
  float lt0 = log_tau2[d], lt1 = log_tau2[256 + d];
  float mc0 = mu_c[d], mc1 = mu_c[256 + d];
  float it0 = expf(-lt0), it1 = expf(-lt1);
  wsc[WS_DIT + d] = it1 - it0;
  wsc[WS_E + d] = mc1 * it1 - mc0 * it0;
  float g = mc1 * mc1 * it1 - mc0 * mc0 * it0 + (lt1 - lt0);
  float sg = block_sum(g, scr);
  if (d == 0) wsc[WS_C0] = (log_prior[1] - log_prior[0]) - 0.5f * sg;
}

// ---------------------------------------------------------------------------
// Token kernel: 64 tokens per block, 256 threads.
// Per chunk c (8 chunks): stage A-tile [64 k-rows x 64 tok] in LDS where
// k-rows 0..31 = mu[d in c*32..c*32+31], 32..63 = logvar[same d]; stage
// B-tile [64 k x 128 h] = W1 columns. GEMM accum (each thread 4 tok x 8 h)
// + phase-A partial reductions from the same LDS data.
// ---------------------------------------------------------------------------
__global__ __launch_bounds__(256) void k_token(
    const float* __restrict__ mu, const float* __restrict__ logvar,
    const float* __restrict__ minutes, const float* __restrict__ W1,
    const float* __restrict__ b1, const float* __restrict__ W2,
    const float* __restrict__ b2, const float* __restrict__ wsc,
    float* __restrict__ out_s, float* __restrict__ ws_score,
    float* __restrict__ ws_araw) {
  __shared__ __align__(16) float A_l[64][65];    // [k][tok]
  __shared__ __align__(16) float B_l[64][132];   // [k][h]
  __shared__ float dit_l[256];
  __shared__ float e_l[256];
  __shared__ float wx_l[128][8];  // [h][{w512..w516, b1, w2}]
  __shared__ float ex_l[64][5];   // [tok][{s, minutes, snr1, snr2, snr3}]
  __shared__ __align__(16) float red_l[4][64][4];
  __shared__ __align__(16) float red2[4][16][4];

  const int tid = threadIdx.x;
  const int tokbase = blockIdx.x * 64;
  const int tg = tid & 15;   // token group (4 tokens: tg, tg+16, tg+32, tg+48)
  const int hg = tid >> 4;   // h group (8 h: hg*8 .. hg*8+7)
  const int tokp = tid & 63; // phase-A token
  const int p = tid >> 6;    // phase-A d-part (= wave id)

  // stage constants
  dit_l[tid] = wsc[WS_DIT + tid];
  e_l[tid] = wsc[WS_E + tid];
  if (tid < 128) {
    const float* wr = W1 + tid * W1_LD;
    wx_l[tid][0] = wr[512];
    wx_l[tid][1] = wr[513];
    wx_l[tid][2] = wr[514];
    wx_l[tid][3] = wr[515];
    wx_l[tid][4] = wr[516];
    wx_l[tid][5] = b1[tid];
    wx_l[tid][6] = W2[tid];
  }
  const float C0 = wsc[WS_C0];

  float acc[4][8];
#pragma unroll
  for (int i = 0; i < 4; ++i)
#pragma unroll
    for (int j = 0; j < 8; ++j) acc[i][j] = 0.0f;

  float pa_s = 0.f, pa_m2 = 0.f, pa_lv = 0.f, pa_sc = 0.f;

  for (int c = 0; c < 8; ++c) {
    __syncthreads();  // previous chunk fully consumed (and const staging done)
    // stage A: 64 tok x 32 d for mu and logvar (coalesced 128B per token row)
#pragma unroll
    for (int t = 0; t < 8; ++t) {
      int idx = tid + t * 256;
      int tok = idx >> 5;
      int j = idx & 31;
      int g = (tokbase + tok) * 256 + c * 32 + j;
      A_l[j][tok] = mu[g];
      A_l[32 + j][tok] = logvar[g];
    }
    // stage B: W1 columns [c*32 .. +31] (mu part) and [256+c*32 .. +31] (lv)
#pragma unroll
    for (int t = 0; t < 32; ++t) {
      int idx = tid + t * 256;
      int h = idx >> 6;
      int j = idx & 63;
      int col = (j < 32) ? (c * 32 + j) : (256 + c * 32 + (j - 32));
      B_l[j][h] = W1[h * W1_LD + col];
    }
    __syncthreads();
    // GEMM over this chunk
    for (int k = 0; k < 64; ++k) {
      float av[4];
      av[0] = A_l[k][tg];
      av[1] = A_l[k][tg + 16];
      av[2] = A_l[k][tg + 32];
      av[3] = A_l[k][tg + 48];
      float4 bA = *(const float4*)&B_l[k][hg * 8];
      float4 bB = *(const float4*)&B_l[k][hg * 8 + 4];
      float bv[8] = {bA.x, bA.y, bA.z, bA.w, bB.x, bB.y, bB.z, bB.w};
#pragma unroll
      for (int i = 0; i < 4; ++i)
#pragma unroll
        for (int j = 0; j < 8; ++j) acc[i][j] = fmaf(av[i], bv[j], acc[i][j]);
    }
    // phase-A partial reductions from the same staged data
#pragma unroll
    for (int j = 0; j < 8; ++j) {
      int dl = p * 8 + j;
      int d = c * 32 + dl;
      float m = A_l[dl][tokp];
      float l = A_l[32 + dl][tokp];
      float var = expf(l);
      float vc = fmaxf(var, 1e-6f);
      float m2 = m * m;
      pa_s += (var + m2) * dit_l[d] - 2.0f * m * e_l[d];
      pa_m2 += m2;
      pa_lv += l;
      pa_sc += m2 / vc;
    }
  }

  red_l[p][tokp][0] = pa_s;
  red_l[p][tokp][1] = pa_m2;
  red_l[p][tokp][2] = pa_lv;
  red_l[p][tokp][3] = pa_sc;
  __syncthreads();
  if (tid < 64) {
    float Ss = 0.f, Sm = 0.f, Sl = 0.f, Sc = 0.f;
#pragma unroll
    for (int q = 0; q < 4; ++q) {
      Ss += red_l[q][tid][0];
      Sm += red_l[q][tid][1];
      Sl += red_l[q][tid][2];
      Sc += red_l[q][tid][3];
    }
    float sval = -0.5f * Ss + C0;
    float mn = minutes[tokbase + tid];
    ex_l[tid][0] = sval;
    ex_l[tid][1] = mn;
    ex_l[tid][2] = sqrtf(Sm) * (1.0f / 16.0f);   // snr1 = ||mu||/sqrt(256)
    ex_l[tid][3] = Sl * (1.0f / 256.0f);         // snr2
    ex_l[tid][4] = Sc * (1.0f / 256.0f);         // snr3
    out_s[tokbase + tid] = sval;
    ws_score[tokbase + tid] = Sc;                // score
  }
  __syncthreads();

  // epilogue: add extras, relu, dot with W2, cross-lane + cross-wave reduce
  float ct[4];
#pragma unroll
  for (int i = 0; i < 4; ++i) {
    int tok = tg + 16 * i;
    float sv = ex_l[tok][0];
    float mn = ex_l[tok][1];
    float s1 = ex_l[tok][2];
    float s2 = ex_l[tok][3];
    float s3 = ex_l[tok][4];
    float csum = 0.f;
#pragma unroll
    for (int j = 0; j < 8; ++j) {
      int h = hg * 8 + j;
      float hp = acc[i][j] + sv * wx_l[h][0] + mn * wx_l[h][1] +
                 s1 * wx_l[h][2] + s2 * wx_l[h][3] + s3 * wx_l[h][4] +
                 wx_l[h][5];
      hp = fmaxf(hp, 0.0f);
      csum = fmaf(hp, wx_l[h][6], csum);
    }
    ct[i] = csum;
  }
#pragma unroll
  for (int i = 0; i < 4; ++i) {
    ct[i] += __shfl_xor(ct[i], 16, 64);
    ct[i] += __shfl_xor(ct[i], 32, 64);
  }
  int wid = tid >> 6;
  if ((tid & 63) < 16) {
    red2[wid][tg][0] = ct[0];
    red2[wid][tg][1] = ct[1];
    red2[wid][tg][2] = ct[2];
    red2[wid][tg][3] = ct[3];
  }
  __syncthreads();
  if (tid < 64) {
    int tg2 = tid & 15;
    int i2 = tid >> 4;  // tok = tg2 + 16*i2 == tid
    float z = red2[0][tg2][i2] + red2[1][tg2][i2] + red2[2][tg2][i2] +
              red2[3][tg2][i2] + b2[0];
    ws_araw[tokbase + tid] = 1.0f / (1.0f + expf(-z));
  }
}

// ---------------------------------------------------------------------------
// Per-batch-row kernel: 256 blocks (one per b), 256 threads x 2 tokens.
// ---------------------------------------------------------------------------
__global__ __launch_bounds__(256) void k_row(
    const float* __restrict__ minutes, const float* __restrict__ s_in,
    const float* __restrict__ score_in, const float* __restrict__ araw_in,
    const float* __restrict__ alpha_logits,
    const float* __restrict__ attn_lambda_logit,
    const float* __restrict__ decay_rate_log, float* __restrict__ out_total,
    float* __restrict__ out_a) {
  __shared__ float scr[4];
  int row = blockIdx.x;
  int tid = threadIdx.x;
  int base = row * 512;
  float sc0 = score_in[base + tid], sc1 = score_in[base + 256 + tid];
  float sv0 = s_in[base + tid], sv1 = s_in[base + 256 + tid];
  float ar0 = araw_in[base + tid], ar1 = araw_in[base + 256 + tid];
  float mn0 = minutes[base + tid], mn1 = minutes[base + 256 + tid];

  float msc = block_max(fmaxf(sc0, sc1), scr);
  float mmn = block_max(fmaxf(mn0, mn1), scr);
  float sar = block_sum(ar0 + ar1, scr);
  float e0 = expf(sc0 - msc), e1 = expf(sc1 - msc);
  float se = block_sum(e0 + e1, scr);

  float lam = 1.0f / (1.0f + expf(-attn_lambda_logit[0]));
  float alpha = 1.0f / (1.0f + expf(-alpha_logits[0]));
  float rate = log1pf(expf(decay_rate_log[0]));

  float inv_sar = 1.0f / fmaxf(sar, 1e-6f);
  float inv_se = 1.0f / se;
  float a00 = lam * ar0 * inv_sar + (1.0f - lam) * e0 * inv_se;
  float a01 = lam * ar1 * inv_sar + (1.0f - lam) * e1 * inv_se;
  float dh0 = fmaxf(mmn - mn0, 0.0f) * (1.0f / 60.0f);
  float dh1 = fmaxf(mmn - mn1, 0.0f) * (1.0f / 60.0f);
  float w0 = a00 * expf(-rate * dh0);
  float w1 = a01 * expf(-rate * dh1);
  float sw = block_sum(w0 + w1, scr);
  float inv_sw = 1.0f / fmaxf(sw, 1e-6f);
  float af0 = w0 * inv_sw, af1 = w1 * inv_sw;
  out_a[base + tid] = af0;
  out_a[base + 256 + tid] = af1;
  float smain = block_sum(af0 * sv0 + af1 * sv1, scr);
  float sg0 = 1.0f / (1.0f + expf(-sv0));
  float sg1 = 1.0f / (1.0f + expf(-sv1));
  float p0 = fminf(fmaxf(sg0 * af0, 1e-6f), 1.0f - 1e-6f);
  float p1 = fminf(fmaxf(sg1 * af1, 1e-6f), 1.0f - 1e-6f);
  float slg = block_sum(log1pf(-p0) + log1pf(-p1), scr);
  if (tid == 0) {
    float por = 1.0f - expf(slg);
    por = fminf(fmaxf(por, 1e-6f), 1.0f - 1e-6f);
    float sor = logf(por) - log1pf(-por);
    out_total[row] = alpha * smain + (1.0f - alpha) * sor;
  }
}

extern "C" void kernel_launch(void* const* d_in, const int* in_sizes, int n_in,
                              void* d_out, int out_size, void* d_ws,
                              size_t ws_size, hipStream_t stream) {
  const float* mu = (const float*)d_in[0];
  const float* logvar = (const float*)d_in[1];
  const float* minutes = (const float*)d_in[2];
  const float* mu_c = (const float*)d_in[3];
  const float* log_tau2 = (const float*)d_in[4];
  const float* log_prior = (const float*)d_in[5];
  const float* W1 = (const float*)d_in[6];
  const float* b1 = (const float*)d_in[7];
  const float* W2 = (const float*)d_in[8];
  const float* b2 = (const float*)d_in[9];
  const float* alpha_logits = (const float*)d_in[10];
  const float* attn_lambda_logit = (const float*)d_in[11];
  const float* decay_rate_log = (const float*)d_in[12];

  float* out = (float*)d_out;
  float* out_total = out;                   // [256]
  float* out_s = out + B_DIM;               // [131072]
  float* out_a = out + B_DIM + NTOK;        // [131072]
  float* wsc = (float*)d_ws;
  float* ws_score = wsc + WS_SCORE;
  float* ws_araw = wsc + WS_ARAW;

  k_setup<<<1, 256, 0, stream>>>(mu_c, log_tau2, log_prior, wsc);
  k_token<<<NTOK / 64, 256, 0, stream>>>(mu, logvar, minutes, W1, b1, W2, b2,
                                         wsc, out_s, ws_score, ws_araw);
  k_row<<<B_DIM, 256, 0, stream>>>(minutes, out_s, ws_score, ws_araw,
                                   alpha_logits, attn_lambda_logit,
                                   decay_rate_log, out_total, out_a);
}

// Round 2
// 115.256 us; speedup vs baseline: 2.5236x; 2.5236x over previous
//
#include <hip/hip_runtime.h>
#include <hip/hip_bf16.h>

#define B_DIM 256
#define NTOK (256 * 512)
#define W1_LD 517
#define TPB 32  // tokens per k_token block

// workspace float offsets
#define WS_DIT 0
#define WS_E 256
#define WS_C0 512
#define WS_WX 576            // [128][7]
#define WS_W1B 2048          // bf16 [128][512] = 32768 floats
#define WS_SCORE 34816       // [NTOK]

typedef __attribute__((ext_vector_type(8))) short bf16x8;
typedef __attribute__((ext_vector_type(4))) float f32x4;

__device__ __forceinline__ ushort f2bf(float f) {
  union { float f; unsigned u; } v; v.f = f;
  unsigned r = v.u + 0x7FFFu + ((v.u >> 16) & 1u);
  return (ushort)(r >> 16);
}
__device__ __forceinline__ unsigned long long pack4bf(float a, float b, float c,
                                                      float d) {
  return (unsigned long long)f2bf(a) | ((unsigned long long)f2bf(b) << 16) |
         ((unsigned long long)f2bf(c) << 32) |
         ((unsigned long long)f2bf(d) << 48);
}

__device__ __forceinline__ float wave_sum(float v) {
#pragma unroll
  for (int off = 32; off > 0; off >>= 1) v += __shfl_xor(v, off, 64);
  return v;
}
__device__ __forceinline__ float wave_max(float v) {
#pragma unroll
  for (int off = 32; off > 0; off >>= 1) v = fmaxf(v, __shfl_xor(v, off, 64));
  return v;
}
__device__ __forceinline__ float block_sum(float v, float* scr) {
  v = wave_sum(v);
  int wid = threadIdx.x >> 6;
  __syncthreads();
  if ((threadIdx.x & 63) == 0) scr[wid] = v;
  __syncthreads();
  return scr[0] + scr[1] + scr[2] + scr[3];
}
__device__ __forceinline__ float block_max(float v, float* scr) {
  v = wave_max(v);
  int wid = threadIdx.x >> 6;
  __syncthreads();
  if ((threadIdx.x & 63) == 0) scr[wid] = v;
  __syncthreads();
  return fmaxf(fmaxf(scr[0], scr[1]), fmaxf(scr[2], scr[3]));
}

// ---------------------------------------------------------------------------
// Setup (grid 128): every block converts one W1 row to bf16; block 0 also
// builds per-d constants + the wx table (W1 tail cols, b1, W2).
// ---------------------------------------------------------------------------
__global__ __launch_bounds__(256) void k_setup(
    const float* __restrict__ W1, const float* __restrict__ b1,
    const float* __restrict__ W2, const float* __restrict__ mu_c,
    const float* __restrict__ log_tau2, const float* __restrict__ log_prior,
    float* __restrict__ wsc) {
  const int tid = threadIdx.x;
  const int h = blockIdx.x;
  ushort* w1b = (ushort*)(wsc + WS_W1B);
  w1b[h * 512 + tid] = f2bf(W1[h * W1_LD + tid]);
  w1b[h * 512 + 256 + tid] = f2bf(W1[h * W1_LD + 256 + tid]);
  if (blockIdx.x == 0) {
    __shared__ float scr[4];
    float lt0 = log_tau2[tid], lt1 = log_tau2[256 + tid];
    float mc0 = mu_c[tid], mc1 = mu_c[256 + tid];
    float it0 = expf(-lt0), it1 = expf(-lt1);
    wsc[WS_DIT + tid] = it1 - it0;
    wsc[WS_E + tid] = mc1 * it1 - mc0 * it0;
    float g = mc1 * mc1 * it1 - mc0 * mc0 * it0 + (lt1 - lt0);
    float sg = block_sum(g, scr);
    if (tid == 0) wsc[WS_C0] = (log_prior[1] - log_prior[0]) - 0.5f * sg;
    if (tid < 128) {
      const float* wr = W1 + tid * W1_LD;
      float* wx = wsc + WS_WX + tid * 7;
      wx[0] = wr[512];
      wx[1] = wr[513];
      wx[2] = wr[514];
      wx[3] = wr[515];
      wx[4] = wr[516];
      wx[5] = b1[tid];
      wx[6] = W2[tid];
    }
  }
}

// ---------------------------------------------------------------------------
// Token kernel: 32 tokens/block, 256 threads (4 waves).
// Phase 1: stream mu/logvar (float4, coalesced), phase-A partials in regs
//          (shfl-reduce), bf16 A-tile into XOR-swizzled LDS.
// Phase 2: MFMA 16x16x32_bf16: M=32 (2 frags), per-wave N=32 (2 frags),
//          K=512 (16 steps). B frags straight from L2-resident bf16 W1.
// ---------------------------------------------------------------------------
__global__ __launch_bounds__(256) void k_token(
    const float* __restrict__ mu, const float* __restrict__ logvar,
    const float* __restrict__ minutes, const float* __restrict__ b2,
    const float* __restrict__ wsc, float* __restrict__ out_s,
    float* __restrict__ ws_score, float* __restrict__ araw_out) {
  __shared__ __align__(16) ushort A_l[TPB * 512];  // 32KB, byte-XOR swizzled
  __shared__ __align__(16) float4 part[TPB][16];   // 8KB
  __shared__ float wx_l[128][9];                   // padded: stride 9 f32
  __shared__ float ex_l[TPB][5];
  __shared__ float red2[4][TPB];

  const int tid = threadIdx.x;
  const int w = tid >> 6;
  const int l = tid & 63;
  const int tokbase = blockIdx.x * TPB;

  if (tid < 128) {
    const float* wx = wsc + WS_WX + tid * 7;
#pragma unroll
    for (int x = 0; x < 7; ++x) wx_l[tid][x] = wx[x];
  }
  const float C0 = wsc[WS_C0];
  const float4 dit4 = *(const float4*)(wsc + WS_DIT + 4 * l);
  const float4 e4 = *(const float4*)(wsc + WS_E + 4 * l);

  // ---- phase 1: stream + phase-A partials + A-tile staging ----
  char* Ab = (char*)A_l;
#pragma unroll 4
  for (int t = 0; t < 8; ++t) {
    const int row = w * 8 + t;
    const size_t gbase = (size_t)(tokbase + row) * 256 + 4 * l;
    const float4 mv = *(const float4*)(mu + gbase);
    const float4 lvv = *(const float4*)(logvar + gbase);
    const float v0 = expf(lvv.x), v1 = expf(lvv.y), v2 = expf(lvv.z),
                v3 = expf(lvv.w);
    const float q0 = mv.x * mv.x, q1 = mv.y * mv.y, q2 = mv.z * mv.z,
                q3 = mv.w * mv.w;
    float ps = (v0 + q0) * dit4.x - 2.0f * mv.x * e4.x +
               (v1 + q1) * dit4.y - 2.0f * mv.y * e4.y +
               (v2 + q2) * dit4.z - 2.0f * mv.z * e4.z +
               (v3 + q3) * dit4.w - 2.0f * mv.w * e4.w;
    float pm2 = q0 + q1 + q2 + q3;
    float plv = lvv.x + lvv.y + lvv.z + lvv.w;
    float psc = __fdividef(q0, fmaxf(v0, 1e-6f)) +
                __fdividef(q1, fmaxf(v1, 1e-6f)) +
                __fdividef(q2, fmaxf(v2, 1e-6f)) +
                __fdividef(q3, fmaxf(v3, 1e-6f));
    // stage bf16 A-tile (X = [mu | logvar]), swizzled
    const int swz = (row & 7) << 4;
    const int rb = row * 1024;
    *(unsigned long long*)(Ab + ((rb + 8 * l) ^ swz)) =
        pack4bf(mv.x, mv.y, mv.z, mv.w);
    *(unsigned long long*)(Ab + ((rb + 512 + 8 * l) ^ swz)) =
        pack4bf(lvv.x, lvv.y, lvv.z, lvv.w);
    // 2-level reduce: lanes 0..15 hold class sums
    ps += __shfl_xor(ps, 32, 64);
    ps += __shfl_xor(ps, 16, 64);
    pm2 += __shfl_xor(pm2, 32, 64);
    pm2 += __shfl_xor(pm2, 16, 64);
    plv += __shfl_xor(plv, 32, 64);
    plv += __shfl_xor(plv, 16, 64);
    psc += __shfl_xor(psc, 32, 64);
    psc += __shfl_xor(psc, 16, 64);
    if (l < 16) part[row][l ^ (row & 15)] = make_float4(ps, pm2, plv, psc);
  }
  __syncthreads();

  // ---- phase 1b: finish per-token scalars ----
  if (tid < TPB) {
    float Ss = 0.f, Sm = 0.f, Sl = 0.f, Sc = 0.f;
#pragma unroll
    for (int j = 0; j < 16; ++j) {
      float4 p = part[tid][j ^ (tid & 15)];
      Ss += p.x;
      Sm += p.y;
      Sl += p.z;
      Sc += p.w;
    }
    float sval = -0.5f * Ss + C0;
    float mn = minutes[tokbase + tid];
    ex_l[tid][0] = sval;
    ex_l[tid][1] = mn;
    ex_l[tid][2] = sqrtf(Sm) * (1.0f / 16.0f);
    ex_l[tid][3] = Sl * (1.0f / 256.0f);
    ex_l[tid][4] = Sc * (1.0f / 256.0f);
    out_s[tokbase + tid] = sval;
    ws_score[tokbase + tid] = Sc;
  }
  __syncthreads();

  // ---- phase 2: MFMA GEMM h = X * W1^T ----
  f32x4 acc00 = {0.f, 0.f, 0.f, 0.f};
  f32x4 acc01 = {0.f, 0.f, 0.f, 0.f};
  f32x4 acc10 = {0.f, 0.f, 0.f, 0.f};
  f32x4 acc11 = {0.f, 0.f, 0.f, 0.f};
  const int m_lane = l & 15;
  const int kb = (l >> 4) * 8;
  const ushort* w1b = (const ushort*)(wsc + WS_W1B);
  const ushort* bp0 = w1b + (32 * w + m_lane) * 512 + kb;
  const ushort* bp1 = bp0 + 16 * 512;
  const int swzA = (m_lane & 7) << 4;
  const int rowA0 = m_lane * 1024;
  const int rowA1 = (m_lane + 16) * 1024;
#pragma unroll 4
  for (int ks = 0; ks < 16; ++ks) {
    const int kByte = ks * 64 + 2 * kb;
    bf16x8 a0 = *(const bf16x8*)(Ab + ((rowA0 + kByte) ^ swzA));
    bf16x8 a1 = *(const bf16x8*)(Ab + ((rowA1 + kByte) ^ swzA));
    bf16x8 bq0 = *(const bf16x8*)(bp0 + ks * 32);
    bf16x8 bq1 = *(const bf16x8*)(bp1 + ks * 32);
    acc00 = __builtin_amdgcn_mfma_f32_16x16x32_bf16(a0, bq0, acc00, 0, 0, 0);
    acc10 = __builtin_amdgcn_mfma_f32_16x16x32_bf16(a1, bq0, acc10, 0, 0, 0);
    acc01 = __builtin_amdgcn_mfma_f32_16x16x32_bf16(a0, bq1, acc01, 0, 0, 0);
    acc11 = __builtin_amdgcn_mfma_f32_16x16x32_bf16(a1, bq1, acc11, 0, 0, 0);
  }

  // ---- epilogue: extras + relu + W2 dot, reduce over h ----
  const int g = l >> 4;
#pragma unroll
  for (int mf = 0; mf < 2; ++mf) {
    const f32x4 aN0 = mf ? acc10 : acc00;
    const f32x4 aN1 = mf ? acc11 : acc01;
#pragma unroll
    for (int r = 0; r < 4; ++r) {
      const int t_loc = 16 * mf + 4 * g + r;
      const float sv = ex_l[t_loc][0];
      const float mn = ex_l[t_loc][1];
      const float s1 = ex_l[t_loc][2];
      const float s2 = ex_l[t_loc][3];
      const float s3 = ex_l[t_loc][4];
      const int h0 = 32 * w + m_lane;
      const int h1 = h0 + 16;
      float hp0 = aN0[r] + sv * wx_l[h0][0] + mn * wx_l[h0][1] +
                  s1 * wx_l[h0][2] + s2 * wx_l[h0][3] + s3 * wx_l[h0][4] +
                  wx_l[h0][5];
      float hp1 = aN1[r] + sv * wx_l[h1][0] + mn * wx_l[h1][1] +
                  s1 * wx_l[h1][2] + s2 * wx_l[h1][3] + s3 * wx_l[h1][4] +
                  wx_l[h1][5];
      float cs = fmaf(fmaxf(hp0, 0.f), wx_l[h0][6],
                      fmaxf(hp1, 0.f) * wx_l[h1][6]);
      cs += __shfl_xor(cs, 1, 64);
      cs += __shfl_xor(cs, 2, 64);
      cs += __shfl_xor(cs, 4, 64);
      cs += __shfl_xor(cs, 8, 64);
      if (m_lane == 0) red2[w][t_loc] = cs;
    }
  }
  __syncthreads();
  if (tid < TPB) {
    float z = red2[0][tid] + red2[1][tid] + red2[2][tid] + red2[3][tid] + b2[0];
    araw_out[tokbase + tid] = 1.0f / (1.0f + expf(-z));
  }
}

// ---------------------------------------------------------------------------
// Per-batch-row kernel: 256 blocks, 256 threads x 2 tokens.
// a_io holds a_raw on entry (written by k_token), final a on exit.
// ---------------------------------------------------------------------------
__global__ __launch_bounds__(256) void k_row(
    const float* __restrict__ minutes, const float* __restrict__ s_in,
    const float* __restrict__ score_in, float* a_io,
    const float* __restrict__ alpha_logits,
    const float* __restrict__ attn_lambda_logit,
    const float* __restrict__ decay_rate_log, float* __restrict__ out_total) {
  __shared__ float scr[4];
  int row = blockIdx.x;
  int tid = threadIdx.x;
  int base = row * 512;
  float sc0 = score_in[base + tid], sc1 = score_in[base + 256 + tid];
  float sv0 = s_in[base + tid], sv1 = s_in[base + 256 + tid];
  float ar0 = a_io[base + tid], ar1 = a_io[base + 256 + tid];
  float mn0 = minutes[base + tid], mn1 = minutes[base + 256 + tid];

  float msc = block_max(fmaxf(sc0, sc1), scr);
  float mmn = block_max(fmaxf(mn0, mn1), scr);
  float sar = block_sum(ar0 + ar1, scr);
  float e0 = expf(sc0 - msc), e1 = expf(sc1 - msc);
  float se = block_sum(e0 + e1, scr);

  float lam = 1.0f / (1.0f + expf(-attn_lambda_logit[0]));
  float alpha = 1.0f / (1.0f + expf(-alpha_logits[0]));
  float rate = log1pf(expf(decay_rate_log[0]));

  float inv_sar = 1.0f / fmaxf(sar, 1e-6f);
  float inv_se = 1.0f / se;
  float a00 = lam * ar0 * inv_sar + (1.0f - lam) * e0 * inv_se;
  float a01 = lam * ar1 * inv_sar + (1.0f - lam) * e1 * inv_se;
  float dh0 = fmaxf(mmn - mn0, 0.0f) * (1.0f / 60.0f);
  float dh1 = fmaxf(mmn - mn1, 0.0f) * (1.0f / 60.0f);
  float w0 = a00 * expf(-rate * dh0);
  float w1 = a01 * expf(-rate * dh1);
  float sw = block_sum(w0 + w1, scr);
  float inv_sw = 1.0f / fmaxf(sw, 1e-6f);
  float af0 = w0 * inv_sw, af1 = w1 * inv_sw;
  a_io[base + tid] = af0;
  a_io[base + 256 + tid] = af1;
  float smain = block_sum(af0 * sv0 + af1 * sv1, scr);
  float sg0 = 1.0f / (1.0f + expf(-sv0));
  float sg1 = 1.0f / (1.0f + expf(-sv1));
  float p0 = fminf(fmaxf(sg0 * af0, 1e-6f), 1.0f - 1e-6f);
  float p1 = fminf(fmaxf(sg1 * af1, 1e-6f), 1.0f - 1e-6f);
  float slg = block_sum(log1pf(-p0) + log1pf(-p1), scr);
  if (tid == 0) {
    float por = 1.0f - expf(slg);
    por = fminf(fmaxf(por, 1e-6f), 1.0f - 1e-6f);
    float sor = logf(por) - log1pf(-por);
    out_total[row] = alpha * smain + (1.0f - alpha) * sor;
  }
}

extern "C" void kernel_launch(void* const* d_in, const int* in_sizes, int n_in,
                              void* d_out, int out_size, void* d_ws,
                              size_t ws_size, hipStream_t stream) {
  const float* mu = (const float*)d_in[0];
  const float* logvar = (const float*)d_in[1];
  const float* minutes = (const float*)d_in[2];
  const float* mu_c = (const float*)d_in[3];
  const float* log_tau2 = (const float*)d_in[4];
  const float* log_prior = (const float*)d_in[5];
  const float* W1 = (const float*)d_in[6];
  const float* b1 = (const float*)d_in[7];
  const float* W2 = (const float*)d_in[8];
  const float* b2 = (const float*)d_in[9];
  const float* alpha_logits = (const float*)d_in[10];
  const float* attn_lambda_logit = (const float*)d_in[11];
  const float* decay_rate_log = (const float*)d_in[12];

  float* out = (float*)d_out;
  float* out_total = out;             // [256]
  float* out_s = out + B_DIM;        // [131072]
  float* out_a = out + B_DIM + NTOK; // [131072] — holds a_raw between kernels
  float* wsc = (float*)d_ws;
  float* ws_score = wsc + WS_SCORE;

  k_setup<<<128, 256, 0, stream>>>(W1, b1, W2, mu_c, log_tau2, log_prior, wsc);
  k_token<<<NTOK / TPB, 256, 0, stream>>>(mu, logvar, minutes, b2, wsc, out_s,
                                          ws_score, out_a);
  k_row<<<B_DIM, 256, 0, stream>>>(minutes, out_s, ws_score, out_a,
                                   alpha_logits, attn_lambda_logit,
                                   decay_rate_log, out_total);
}

// Round 3
// 75.444 us; speedup vs baseline: 3.8553x; 1.5277x over previous
//
#include <hip/hip_runtime.h>
#include <hip/hip_bf16.h>

#define B_DIM 256
#define NTOK (256 * 512)
#define W1_LD 517
#define TPB 32  // tokens per k_token block

// workspace float offsets
#define WS_DIT 0
#define WS_E 256             // holds 2*e
#define WS_C0 512
#define WS_WX 576            // [128][7]
#define WS_W1F 2048          // bf16 frag-ordered [8 nblk][16 ks][64 lane][8]
#define WS_SCORE 34816       // [NTOK]

typedef __attribute__((ext_vector_type(8))) short bf16x8;
typedef __attribute__((ext_vector_type(4))) float f32x4;

__device__ __forceinline__ unsigned pk2(float a, float b) {
  __hip_bfloat162 h = __float22bfloat162_rn(make_float2(a, b));
  unsigned r;
  __builtin_memcpy(&r, &h, 4);
  return r;
}

__device__ __forceinline__ float wave_sum(float v) {
#pragma unroll
  for (int off = 32; off > 0; off >>= 1) v += __shfl_xor(v, off, 64);
  return v;
}
__device__ __forceinline__ float wave_max(float v) {
#pragma unroll
  for (int off = 32; off > 0; off >>= 1) v = fmaxf(v, __shfl_xor(v, off, 64));
  return v;
}
__device__ __forceinline__ float block_sum(float v, float* scr) {
  v = wave_sum(v);
  int wid = threadIdx.x >> 6;
  __syncthreads();
  if ((threadIdx.x & 63) == 0) scr[wid] = v;
  __syncthreads();
  return scr[0] + scr[1] + scr[2] + scr[3];
}
__device__ __forceinline__ float block_max(float v, float* scr) {
  v = wave_max(v);
  int wid = threadIdx.x >> 6;
  __syncthreads();
  if ((threadIdx.x & 63) == 0) scr[wid] = v;
  __syncthreads();
  return fmaxf(fmaxf(scr[0], scr[1]), fmaxf(scr[2], scr[3]));
}

// ---------------------------------------------------------------------------
// Setup (grid 128): block h converts W1 row h into fragment-ordered bf16
// W1F[n>>4][k>>5][((k>>3)&3)*16 + (n&15)][k&7]; block 0 also builds per-d
// constants (dit, 2e, C0) and the wx table (W1 tail cols, b1, W2).
// ---------------------------------------------------------------------------
__global__ __launch_bounds__(256) void k_setup(
    const float* __restrict__ W1, const float* __restrict__ b1,
    const float* __restrict__ W2, const float* __restrict__ mu_c,
    const float* __restrict__ log_tau2, const float* __restrict__ log_prior,
    float* __restrict__ wsc) {
  const int tid = threadIdx.x;
  const int h = blockIdx.x;
  ushort* w1f = (ushort*)(wsc + WS_W1F);
  const float* wr = W1 + h * W1_LD;
  const int k = 2 * tid;
  const unsigned pk = pk2(wr[k], wr[k + 1]);
  const int flat = (h >> 4) * 8192 + (k >> 5) * 512 +
                   (((k >> 3) & 3) * 16 + (h & 15)) * 8 + (k & 7);
  *(unsigned*)(w1f + flat) = pk;

  if (blockIdx.x == 0) {
    __shared__ float scr[4];
    float lt0 = log_tau2[tid], lt1 = log_tau2[256 + tid];
    float mc0 = mu_c[tid], mc1 = mu_c[256 + tid];
    float it0 = __expf(-lt0), it1 = __expf(-lt1);
    wsc[WS_DIT + tid] = it1 - it0;
    wsc[WS_E + tid] = 2.0f * (mc1 * it1 - mc0 * it0);
    float g = mc1 * mc1 * it1 - mc0 * mc0 * it0 + (lt1 - lt0);
    float sg = block_sum(g, scr);
    if (tid == 0) wsc[WS_C0] = (log_prior[1] - log_prior[0]) - 0.5f * sg;
    if (tid < 128) {
      const float* w1r = W1 + tid * W1_LD;
      float* wx = wsc + WS_WX + tid * 7;
      wx[0] = w1r[512];
      wx[1] = w1r[513];
      wx[2] = w1r[514];
      wx[3] = w1r[515];
      wx[4] = w1r[516];
      wx[5] = b1[tid];
      wx[6] = W2[tid];
    }
  }
}

// ---------------------------------------------------------------------------
// Token kernel: 32 tokens/block, 256 threads (4 waves).
// Phase 1: each thread owns ONE token (8 lanes/token x 32 d per iter);
//          phase-A partials accumulate in registers, reduced once via 12
//          shfl at the end; bf16 A-tile staged into XOR-swizzled LDS.
// Phase 2: MFMA 16x16x32_bf16, M=32, per-wave N=32, K=512 (16 steps);
//          B frags are contiguous 1KB wave reads from L2-resident W1F.
// ---------------------------------------------------------------------------
__global__ __launch_bounds__(256, 4) void k_token(
    const float* __restrict__ mu, const float* __restrict__ logvar,
    const float* __restrict__ minutes, const float* __restrict__ b2,
    const float* __restrict__ wsc, float* __restrict__ out_s,
    float* __restrict__ ws_score, float* __restrict__ araw_out) {
  __shared__ __align__(16) ushort A_l[TPB * 512];  // 32KB, byte-XOR swizzled
  __shared__ float dit_l[256];
  __shared__ float e_l[256];
  __shared__ float wx_l[128][7];  // stride 7 f32 -> conflict-free
  __shared__ float ex_l[TPB][5];
  __shared__ float red2[4][TPB];

  const int tid = threadIdx.x;
  const int w = tid >> 6;
  const int l = tid & 63;
  const int tokbase = blockIdx.x * TPB;

  dit_l[tid] = wsc[WS_DIT + tid];
  e_l[tid] = wsc[WS_E + tid];
  if (tid < 128) {
    const float* wx = wsc + WS_WX + tid * 7;
#pragma unroll
    for (int x = 0; x < 7; ++x) wx_l[tid][x] = wx[x];
  }
  const float C0 = wsc[WS_C0];
  __syncthreads();

  // ---- phase 1: stream + in-register phase-A partials + A-tile staging ----
  const int trow = w * 8 + (l >> 3);  // this thread's token (fixed)
  const int dq = l & 7;               // d-octant within each 32-chunk
  const int swz = (trow & 7) << 4;
  char* Ab = (char*)A_l;
  const size_t gbase = (size_t)(tokbase + trow) * 256 + dq * 4;
  float Ss = 0.f, Sm = 0.f, Sl = 0.f, Sc = 0.f;
#pragma unroll 4
  for (int t = 0; t < 8; ++t) {
    const float4 mv = *(const float4*)(mu + gbase + t * 32);
    const float4 lvv = *(const float4*)(logvar + gbase + t * 32);
    const float4 dit = *(const float4*)&dit_l[t * 32 + dq * 4];
    const float4 e2 = *(const float4*)&e_l[t * 32 + dq * 4];
    const float v0 = __expf(lvv.x), v1 = __expf(lvv.y), v2 = __expf(lvv.z),
                v3 = __expf(lvv.w);
    const float q0 = mv.x * mv.x, q1 = mv.y * mv.y, q2 = mv.z * mv.z,
                q3 = mv.w * mv.w;
    Ss += (v0 + q0) * dit.x - mv.x * e2.x + (v1 + q1) * dit.y - mv.y * e2.y +
          (v2 + q2) * dit.z - mv.z * e2.z + (v3 + q3) * dit.w - mv.w * e2.w;
    Sm += q0 + q1 + q2 + q3;
    Sl += lvv.x + lvv.y + lvv.z + lvv.w;
    Sc += __fdividef(q0, fmaxf(v0, 1e-6f)) +
          __fdividef(q1, fmaxf(v1, 1e-6f)) +
          __fdividef(q2, fmaxf(v2, 1e-6f)) +
          __fdividef(q3, fmaxf(v3, 1e-6f));
    // stage bf16 A-tile (X = [mu | logvar]), swizzled
    const int off = trow * 1024 + t * 64 + dq * 8;
    uint2 um, ul;
    um.x = pk2(mv.x, mv.y);
    um.y = pk2(mv.z, mv.w);
    ul.x = pk2(lvv.x, lvv.y);
    ul.y = pk2(lvv.z, lvv.w);
    *(uint2*)(Ab + (off ^ swz)) = um;
    *(uint2*)(Ab + ((off + 512) ^ swz)) = ul;
  }
  // reduce across the 8 lanes of this token
  Ss += __shfl_xor(Ss, 1, 64); Ss += __shfl_xor(Ss, 2, 64); Ss += __shfl_xor(Ss, 4, 64);
  Sm += __shfl_xor(Sm, 1, 64); Sm += __shfl_xor(Sm, 2, 64); Sm += __shfl_xor(Sm, 4, 64);
  Sl += __shfl_xor(Sl, 1, 64); Sl += __shfl_xor(Sl, 2, 64); Sl += __shfl_xor(Sl, 4, 64);
  Sc += __shfl_xor(Sc, 1, 64); Sc += __shfl_xor(Sc, 2, 64); Sc += __shfl_xor(Sc, 4, 64);
  if (dq == 0) {
    const float sval = -0.5f * Ss + C0;
    const float mn = minutes[tokbase + trow];
    ex_l[trow][0] = sval;
    ex_l[trow][1] = mn;
    ex_l[trow][2] = sqrtf(Sm) * (1.0f / 16.0f);
    ex_l[trow][3] = Sl * (1.0f / 256.0f);
    ex_l[trow][4] = Sc * (1.0f / 256.0f);
    out_s[tokbase + trow] = sval;
    ws_score[tokbase + trow] = Sc;
  }
  __syncthreads();

  // ---- phase 2: MFMA GEMM h = X * W1^T ----
  f32x4 acc00 = {0.f, 0.f, 0.f, 0.f};
  f32x4 acc01 = {0.f, 0.f, 0.f, 0.f};
  f32x4 acc10 = {0.f, 0.f, 0.f, 0.f};
  f32x4 acc11 = {0.f, 0.f, 0.f, 0.f};
  const int m_lane = l & 15;
  const int swzA = (m_lane & 7) << 4;
  const int rowA0 = m_lane * 1024;
  const int rowA1 = rowA0 + 16 * 1024;
  const ushort* w1f = (const ushort*)(wsc + WS_W1F);
  const ushort* bp0 = w1f + (2 * w) * 8192 + l * 8;
  const ushort* bp1 = bp0 + 8192;
#pragma unroll 4
  for (int ks = 0; ks < 16; ++ks) {
    const int kByte = ks * 64 + (l >> 4) * 16;
    bf16x8 a0 = *(const bf16x8*)(Ab + ((rowA0 + kByte) ^ swzA));
    bf16x8 a1 = *(const bf16x8*)(Ab + ((rowA1 + kByte) ^ swzA));
    bf16x8 bq0 = *(const bf16x8*)(bp0 + ks * 512);
    bf16x8 bq1 = *(const bf16x8*)(bp1 + ks * 512);
    acc00 = __builtin_amdgcn_mfma_f32_16x16x32_bf16(a0, bq0, acc00, 0, 0, 0);
    acc10 = __builtin_amdgcn_mfma_f32_16x16x32_bf16(a1, bq0, acc10, 0, 0, 0);
    acc01 = __builtin_amdgcn_mfma_f32_16x16x32_bf16(a0, bq1, acc01, 0, 0, 0);
    acc11 = __builtin_amdgcn_mfma_f32_16x16x32_bf16(a1, bq1, acc11, 0, 0, 0);
  }

  // ---- epilogue: extras + relu + W2 dot, reduce over h ----
  const int g = l >> 4;
#pragma unroll
  for (int mf = 0; mf < 2; ++mf) {
    const f32x4 aN0 = mf ? acc10 : acc00;
    const f32x4 aN1 = mf ? acc11 : acc01;
#pragma unroll
    for (int r = 0; r < 4; ++r) {
      const int t_loc = 16 * mf + 4 * g + r;
      const float sv = ex_l[t_loc][0];
      const float mn = ex_l[t_loc][1];
      const float s1 = ex_l[t_loc][2];
      const float s2 = ex_l[t_loc][3];
      const float s3 = ex_l[t_loc][4];
      const int h0 = 32 * w + m_lane;
      const int h1 = h0 + 16;
      float hp0 = aN0[r] + sv * wx_l[h0][0] + mn * wx_l[h0][1] +
                  s1 * wx_l[h0][2] + s2 * wx_l[h0][3] + s3 * wx_l[h0][4] +
                  wx_l[h0][5];
      float hp1 = aN1[r] + sv * wx_l[h1][0] + mn * wx_l[h1][1] +
                  s1 * wx_l[h1][2] + s2 * wx_l[h1][3] + s3 * wx_l[h1][4] +
                  wx_l[h1][5];
      float cs = fmaf(fmaxf(hp0, 0.f), wx_l[h0][6],
                      fmaxf(hp1, 0.f) * wx_l[h1][6]);
      cs += __shfl_xor(cs, 1, 64);
      cs += __shfl_xor(cs, 2, 64);
      cs += __shfl_xor(cs, 4, 64);
      cs += __shfl_xor(cs, 8, 64);
      if (m_lane == 0) red2[w][t_loc] = cs;
    }
  }
  __syncthreads();
  if (tid < TPB) {
    float z = red2[0][tid] + red2[1][tid] + red2[2][tid] + red2[3][tid] + b2[0];
    araw_out[tokbase + tid] = 1.0f / (1.0f + __expf(-z));
  }
}

// ---------------------------------------------------------------------------
// Per-batch-row kernel: 256 blocks, 256 threads x 2 tokens.
// a_io holds a_raw on entry (written by k_token), final a on exit.
// ---------------------------------------------------------------------------
__global__ __launch_bounds__(256) void k_row(
    const float* __restrict__ minutes, const float* __restrict__ s_in,
    const float* __restrict__ score_in, float* a_io,
    const float* __restrict__ alpha_logits,
    const float* __restrict__ attn_lambda_logit,
    const float* __restrict__ decay_rate_log, float* __restrict__ out_total) {
  __shared__ float scr[4];
  int row = blockIdx.x;
  int tid = threadIdx.x;
  int base = row * 512;
  float sc0 = score_in[base + tid], sc1 = score_in[base + 256 + tid];
  float sv0 = s_in[base + tid], sv1 = s_in[base + 256 + tid];
  float ar0 = a_io[base + tid], ar1 = a_io[base + 256 + tid];
  float mn0 = minutes[base + tid], mn1 = minutes[base + 256 + tid];

  float msc = block_max(fmaxf(sc0, sc1), scr);
  float mmn = block_max(fmaxf(mn0, mn1), scr);
  float sar = block_sum(ar0 + ar1, scr);
  float e0 = __expf(sc0 - msc), e1 = __expf(sc1 - msc);
  float se = block_sum(e0 + e1, scr);

  float lam = 1.0f / (1.0f + __expf(-attn_lambda_logit[0]));
  float alpha = 1.0f / (1.0f + __expf(-alpha_logits[0]));
  float rate = log1pf(__expf(decay_rate_log[0]));

  float inv_sar = 1.0f / fmaxf(sar, 1e-6f);
  float inv_se = 1.0f / se;
  float a00 = lam * ar0 * inv_sar + (1.0f - lam) * e0 * inv_se;
  float a01 = lam * ar1 * inv_sar + (1.0f - lam) * e1 * inv_se;
  float dh0 = fmaxf(mmn - mn0, 0.0f) * (1.0f / 60.0f);
  float dh1 = fmaxf(mmn - mn1, 0.0f) * (1.0f / 60.0f);
  float w0 = a00 * __expf(-rate * dh0);
  float w1 = a01 * __expf(-rate * dh1);
  float sw = block_sum(w0 + w1, scr);
  float inv_sw = 1.0f / fmaxf(sw, 1e-6f);
  float af0 = w0 * inv_sw, af1 = w1 * inv_sw;
  a_io[base + tid] = af0;
  a_io[base + 256 + tid] = af1;
  float smain = block_sum(af0 * sv0 + af1 * sv1, scr);
  float sg0 = 1.0f / (1.0f + __expf(-sv0));
  float sg1 = 1.0f / (1.0f + __expf(-sv1));
  float p0 = fminf(fmaxf(sg0 * af0, 1e-6f), 1.0f - 1e-6f);
  float p1 = fminf(fmaxf(sg1 * af1, 1e-6f), 1.0f - 1e-6f);
  float slg = block_sum(log1pf(-p0) + log1pf(-p1), scr);
  if (tid == 0) {
    float por = 1.0f - __expf(slg);
    por = fminf(fmaxf(por, 1e-6f), 1.0f - 1e-6f);
    float sor = logf(por) - log1pf(-por);
    out_total[row] = alpha * smain + (1.0f - alpha) * sor;
  }
}

extern "C" void kernel_launch(void* const* d_in, const int* in_sizes, int n_in,
                              void* d_out, int out_size, void* d_ws,
                              size_t ws_size, hipStream_t stream) {
  const float* mu = (const float*)d_in[0];
  const float* logvar = (const float*)d_in[1];
  const float* minutes = (const float*)d_in[2];
  const float* mu_c = (const float*)d_in[3];
  const float* log_tau2 = (const float*)d_in[4];
  const float* log_prior = (const float*)d_in[5];
  const float* W1 = (const float*)d_in[6];
  const float* b1 = (const float*)d_in[7];
  const float* W2 = (const float*)d_in[8];
  const float* b2 = (const float*)d_in[9];
  const float* alpha_logits = (const float*)d_in[10];
  const float* attn_lambda_logit = (const float*)d_in[11];
  const float* decay_rate_log = (const float*)d_in[12];

  float* out = (float*)d_out;
  float* out_total = out;             // [256]
  float* out_s = out + B_DIM;        // [131072]
  float* out_a = out + B_DIM + NTOK; // [131072] — holds a_raw between kernels
  float* wsc = (float*)d_ws;
  float* ws_score = wsc + WS_SCORE;

  k_setup<<<128, 256, 0, stream>>>(W1, b1, W2, mu_c, log_tau2, log_prior, wsc);
  k_token<<<NTOK / TPB, 256, 0, stream>>>(mu, logvar, minutes, b2, wsc, out_s,
                                          ws_score, out_a);
  k_row<<<B_DIM, 256, 0, stream>>>(minutes, out_s, ws_score, out_a,
                                   alpha_logits, attn_lambda_logit,
                                   decay_rate_log, out_total);
}

// Round 4
// 74.124 us; speedup vs baseline: 3.9240x; 1.0178x over previous
//
#include <hip/hip_runtime.h>
#include <hip/hip_bf16.h>

#define B_DIM 256
#define NTOK (256 * 512)
#define W1_LD 517
#define TPB 32  // tokens per k_token block

// workspace float offsets
#define WS_DIT 0
#define WS_E 256             // holds 2*e
#define WS_C0 512
#define WS_WX 576            // [128][7]
#define WS_W1F 2048          // bf16 frag-ordered [8 nblk][16 ks][64 lane][8]
#define WS_SCORE 34816       // [NTOK]

typedef __attribute__((ext_vector_type(8))) short bf16x8;
typedef __attribute__((ext_vector_type(4))) float f32x4;

__device__ __forceinline__ unsigned pk2(float a, float b) {
  __hip_bfloat162 h = __float22bfloat162_rn(make_float2(a, b));
  unsigned r;
  __builtin_memcpy(&r, &h, 4);
  return r;
}

__device__ __forceinline__ float wave_sum(float v) {
#pragma unroll
  for (int off = 32; off > 0; off >>= 1) v += __shfl_xor(v, off, 64);
  return v;
}
__device__ __forceinline__ float wave_max(float v) {
#pragma unroll
  for (int off = 32; off > 0; off >>= 1) v = fmaxf(v, __shfl_xor(v, off, 64));
  return v;
}
__device__ __forceinline__ float block_sum(float v, float* scr) {
  v = wave_sum(v);
  int wid = threadIdx.x >> 6;
  __syncthreads();
  if ((threadIdx.x & 63) == 0) scr[wid] = v;
  __syncthreads();
  return scr[0] + scr[1] + scr[2] + scr[3];
}
__device__ __forceinline__ float block_max(float v, float* scr) {
  v = wave_max(v);
  int wid = threadIdx.x >> 6;
  __syncthreads();
  if ((threadIdx.x & 63) == 0) scr[wid] = v;
  __syncthreads();
  return fmaxf(fmaxf(scr[0], scr[1]), fmaxf(scr[2], scr[3]));
}

// ---------------------------------------------------------------------------
// Setup (grid 128): block h converts W1 row h into fragment-ordered bf16
// W1F[n>>4][k>>5][((k>>3)&3)*16 + (n&15)][k&7]; block 0 also builds per-d
// constants (dit, 2e, C0) and the wx table (W1 tail cols, b1, W2).
// ---------------------------------------------------------------------------
__global__ __launch_bounds__(256) void k_setup(
    const float* __restrict__ W1, const float* __restrict__ b1,
    const float* __restrict__ W2, const float* __restrict__ mu_c,
    const float* __restrict__ log_tau2, const float* __restrict__ log_prior,
    float* __restrict__ wsc) {
  const int tid = threadIdx.x;
  const int h = blockIdx.x;
  ushort* w1f = (ushort*)(wsc + WS_W1F);
  const float* wr = W1 + h * W1_LD;
  const int k = 2 * tid;
  const unsigned pk = pk2(wr[k], wr[k + 1]);
  const int flat = (h >> 4) * 8192 + (k >> 5) * 512 +
                   (((k >> 3) & 3) * 16 + (h & 15)) * 8 + (k & 7);
  *(unsigned*)(w1f + flat) = pk;

  if (blockIdx.x == 0) {
    __shared__ float scr[4];
    float lt0 = log_tau2[tid], lt1 = log_tau2[256 + tid];
    float mc0 = mu_c[tid], mc1 = mu_c[256 + tid];
    float it0 = __expf(-lt0), it1 = __expf(-lt1);
    wsc[WS_DIT + tid] = it1 - it0;
    wsc[WS_E + tid] = 2.0f * (mc1 * it1 - mc0 * it0);
    float g = mc1 * mc1 * it1 - mc0 * mc0 * it0 + (lt1 - lt0);
    float sg = block_sum(g, scr);
    if (tid == 0) wsc[WS_C0] = (log_prior[1] - log_prior[0]) - 0.5f * sg;
    if (tid < 128) {
      const float* w1r = W1 + tid * W1_LD;
      float* wx = wsc + WS_WX + tid * 7;
      wx[0] = w1r[512];
      wx[1] = w1r[513];
      wx[2] = w1r[514];
      wx[3] = w1r[515];
      wx[4] = w1r[516];
      wx[5] = b1[tid];
      wx[6] = W2[tid];
    }
  }
}

// ---------------------------------------------------------------------------
// Token kernel: 32 tokens/block, 512 threads (8 waves) -> 4 blocks/CU =
// 32 waves/CU (100% occupancy target; VGPR must stay <= 64).
// Phase 1: 16 lanes/token x 4 float4-pair iters; phase-A partials in regs
//          (4-shfl reduce); bf16 A-tile into XOR-swizzled LDS.
// Phase 2: MFMA 16x16x32_bf16: per-wave N=16 (1 frag), M=32 (2 frags),
//          K=512 (16 steps). B frags from L2-resident frag-ordered W1F.
// ---------------------------------------------------------------------------
__global__ __launch_bounds__(512, 8) void k_token(
    const float* __restrict__ mu, const float* __restrict__ logvar,
    const float* __restrict__ minutes, const float* __restrict__ b2,
    const float* __restrict__ wsc, float* __restrict__ out_s,
    float* __restrict__ ws_score, float* __restrict__ araw_out) {
  __shared__ __align__(16) ushort A_l[TPB * 512];  // 32KB, byte-XOR swizzled
  __shared__ float dit_l[256];
  __shared__ float e_l[256];
  __shared__ float wx_l[128][7];  // stride 7 f32 -> conflict-free
  __shared__ float ex_l[TPB][5];
  __shared__ float red2[8][TPB];

  const int tid = threadIdx.x;
  const int w = tid >> 6;
  const int l = tid & 63;
  const int tokbase = blockIdx.x * TPB;

  if (tid < 256) {
    dit_l[tid] = wsc[WS_DIT + tid];
    e_l[tid] = wsc[WS_E + tid];
  }
  if (tid >= 256 && tid < 384) {
    const int hh = tid - 256;
    const float* wx = wsc + WS_WX + hh * 7;
#pragma unroll
    for (int x = 0; x < 7; ++x) wx_l[hh][x] = wx[x];
  }
  const float C0 = wsc[WS_C0];
  __syncthreads();

  // ---- phase 1: stream + in-register phase-A partials + A-tile staging ----
  const int trow = tid >> 4;   // this thread's token (fixed), 0..31
  const int l16 = tid & 15;    // 16 lanes per token
  const int swz = (trow & 7) << 4;
  char* Ab = (char*)A_l;
  const size_t gbase = (size_t)(tokbase + trow) * 256 + l16 * 4;
  float Ss = 0.f, Sm = 0.f, Sl = 0.f, Sc = 0.f;
#pragma unroll
  for (int t = 0; t < 4; ++t) {
    const float4 mv = *(const float4*)(mu + gbase + t * 64);
    const float4 lvv = *(const float4*)(logvar + gbase + t * 64);
    const float4 dit = *(const float4*)&dit_l[t * 64 + l16 * 4];
    const float4 e2 = *(const float4*)&e_l[t * 64 + l16 * 4];
    const float v0 = __expf(lvv.x), v1 = __expf(lvv.y), v2 = __expf(lvv.z),
                v3 = __expf(lvv.w);
    const float q0 = mv.x * mv.x, q1 = mv.y * mv.y, q2 = mv.z * mv.z,
                q3 = mv.w * mv.w;
    Ss += (v0 + q0) * dit.x - mv.x * e2.x + (v1 + q1) * dit.y - mv.y * e2.y +
          (v2 + q2) * dit.z - mv.z * e2.z + (v3 + q3) * dit.w - mv.w * e2.w;
    Sm += q0 + q1 + q2 + q3;
    Sl += lvv.x + lvv.y + lvv.z + lvv.w;
    Sc += __fdividef(q0, fmaxf(v0, 1e-6f)) +
          __fdividef(q1, fmaxf(v1, 1e-6f)) +
          __fdividef(q2, fmaxf(v2, 1e-6f)) +
          __fdividef(q3, fmaxf(v3, 1e-6f));
    // stage bf16 A-tile (X = [mu | logvar]), swizzled
    const int off = trow * 1024 + t * 128 + l16 * 8;
    uint2 um, ul;
    um.x = pk2(mv.x, mv.y);
    um.y = pk2(mv.z, mv.w);
    ul.x = pk2(lvv.x, lvv.y);
    ul.y = pk2(lvv.z, lvv.w);
    *(uint2*)(Ab + (off ^ swz)) = um;
    *(uint2*)(Ab + ((off + 512) ^ swz)) = ul;
  }
  // reduce across the 16 lanes of this token
  Ss += __shfl_xor(Ss, 1, 64); Ss += __shfl_xor(Ss, 2, 64);
  Ss += __shfl_xor(Ss, 4, 64); Ss += __shfl_xor(Ss, 8, 64);
  Sm += __shfl_xor(Sm, 1, 64); Sm += __shfl_xor(Sm, 2, 64);
  Sm += __shfl_xor(Sm, 4, 64); Sm += __shfl_xor(Sm, 8, 64);
  Sl += __shfl_xor(Sl, 1, 64); Sl += __shfl_xor(Sl, 2, 64);
  Sl += __shfl_xor(Sl, 4, 64); Sl += __shfl_xor(Sl, 8, 64);
  Sc += __shfl_xor(Sc, 1, 64); Sc += __shfl_xor(Sc, 2, 64);
  Sc += __shfl_xor(Sc, 4, 64); Sc += __shfl_xor(Sc, 8, 64);
  if (l16 == 0) {
    const float sval = -0.5f * Ss + C0;
    const float mn = minutes[tokbase + trow];
    ex_l[trow][0] = sval;
    ex_l[trow][1] = mn;
    ex_l[trow][2] = sqrtf(Sm) * (1.0f / 16.0f);
    ex_l[trow][3] = Sl * (1.0f / 256.0f);
    ex_l[trow][4] = Sc * (1.0f / 256.0f);
    out_s[tokbase + trow] = sval;
    ws_score[tokbase + trow] = Sc;
  }
  __syncthreads();

  // ---- phase 2: MFMA GEMM h = X * W1^T (wave w owns h in [16w,16w+16)) ----
  f32x4 acc0 = {0.f, 0.f, 0.f, 0.f};
  f32x4 acc1 = {0.f, 0.f, 0.f, 0.f};
  const int m_lane = l & 15;
  const int swzA = (m_lane & 7) << 4;
  const int rowA0 = m_lane * 1024;
  const int rowA1 = rowA0 + 16 * 1024;
  const ushort* bp = (const ushort*)(wsc + WS_W1F) + w * 8192 + l * 8;
#pragma unroll 4
  for (int ks = 0; ks < 16; ++ks) {
    const int kByte = ks * 64 + (l >> 4) * 16;
    bf16x8 a0 = *(const bf16x8*)(Ab + ((rowA0 + kByte) ^ swzA));
    bf16x8 a1 = *(const bf16x8*)(Ab + ((rowA1 + kByte) ^ swzA));
    bf16x8 bq = *(const bf16x8*)(bp + ks * 512);
    acc0 = __builtin_amdgcn_mfma_f32_16x16x32_bf16(a0, bq, acc0, 0, 0, 0);
    acc1 = __builtin_amdgcn_mfma_f32_16x16x32_bf16(a1, bq, acc1, 0, 0, 0);
  }

  // ---- epilogue: extras + relu + W2 dot, reduce over h ----
  const int g = l >> 4;
  const int h0 = 16 * w + m_lane;
  const float wxa = wx_l[h0][0], wxb = wx_l[h0][1], wxc = wx_l[h0][2],
              wxd = wx_l[h0][3], wxe = wx_l[h0][4], wxf = wx_l[h0][5],
              wxg = wx_l[h0][6];
#pragma unroll
  for (int mf = 0; mf < 2; ++mf) {
    const f32x4 aN = mf ? acc1 : acc0;
#pragma unroll
    for (int r = 0; r < 4; ++r) {
      const int t_loc = 16 * mf + 4 * g + r;
      float hp = aN[r] + ex_l[t_loc][0] * wxa + ex_l[t_loc][1] * wxb +
                 ex_l[t_loc][2] * wxc + ex_l[t_loc][3] * wxd +
                 ex_l[t_loc][4] * wxe + wxf;
      float cs = fmaxf(hp, 0.f) * wxg;
      cs += __shfl_xor(cs, 1, 64);
      cs += __shfl_xor(cs, 2, 64);
      cs += __shfl_xor(cs, 4, 64);
      cs += __shfl_xor(cs, 8, 64);
      if (m_lane == 0) red2[w][t_loc] = cs;
    }
  }
  __syncthreads();
  if (tid < TPB) {
    float z = red2[0][tid] + red2[1][tid] + red2[2][tid] + red2[3][tid] +
              red2[4][tid] + red2[5][tid] + red2[6][tid] + red2[7][tid] +
              b2[0];
    araw_out[tokbase + tid] = 1.0f / (1.0f + __expf(-z));
  }
}

// ---------------------------------------------------------------------------
// Per-batch-row kernel: 256 blocks, 256 threads x 2 tokens.
// a_io holds a_raw on entry (written by k_token), final a on exit.
// ---------------------------------------------------------------------------
__global__ __launch_bounds__(256) void k_row(
    const float* __restrict__ minutes, const float* __restrict__ s_in,
    const float* __restrict__ score_in, float* a_io,
    const float* __restrict__ alpha_logits,
    const float* __restrict__ attn_lambda_logit,
    const float* __restrict__ decay_rate_log, float* __restrict__ out_total) {
  __shared__ float scr[4];
  int row = blockIdx.x;
  int tid = threadIdx.x;
  int base = row * 512;
  float sc0 = score_in[base + tid], sc1 = score_in[base + 256 + tid];
  float sv0 = s_in[base + tid], sv1 = s_in[base + 256 + tid];
  float ar0 = a_io[base + tid], ar1 = a_io[base + 256 + tid];
  float mn0 = minutes[base + tid], mn1 = minutes[base + 256 + tid];

  float msc = block_max(fmaxf(sc0, sc1), scr);
  float mmn = block_max(fmaxf(mn0, mn1), scr);
  float sar = block_sum(ar0 + ar1, scr);
  float e0 = __expf(sc0 - msc), e1 = __expf(sc1 - msc);
  float se = block_sum(e0 + e1, scr);

  float lam = 1.0f / (1.0f + __expf(-attn_lambda_logit[0]));
  float alpha = 1.0f / (1.0f + __expf(-alpha_logits[0]));
  float rate = log1pf(__expf(decay_rate_log[0]));

  float inv_sar = 1.0f / fmaxf(sar, 1e-6f);
  float inv_se = 1.0f / se;
  float a00 = lam * ar0 * inv_sar + (1.0f - lam) * e0 * inv_se;
  float a01 = lam * ar1 * inv_sar + (1.0f - lam) * e1 * inv_se;
  float dh0 = fmaxf(mmn - mn0, 0.0f) * (1.0f / 60.0f);
  float dh1 = fmaxf(mmn - mn1, 0.0f) * (1.0f / 60.0f);
  float w0 = a00 * __expf(-rate * dh0);
  float w1 = a01 * __expf(-rate * dh1);
  float sw = block_sum(w0 + w1, scr);
  float inv_sw = 1.0f / fmaxf(sw, 1e-6f);
  float af0 = w0 * inv_sw, af1 = w1 * inv_sw;
  a_io[base + tid] = af0;
  a_io[base + 256 + tid] = af1;
  float smain = block_sum(af0 * sv0 + af1 * sv1, scr);
  float sg0 = 1.0f / (1.0f + __expf(-sv0));
  float sg1 = 1.0f / (1.0f + __expf(-sv1));
  float p0 = fminf(fmaxf(sg0 * af0, 1e-6f), 1.0f - 1e-6f);
  float p1 = fminf(fmaxf(sg1 * af1, 1e-6f), 1.0f - 1e-6f);
  float slg = block_sum(log1pf(-p0) + log1pf(-p1), scr);
  if (tid == 0) {
    float por = 1.0f - __expf(slg);
    por = fminf(fmaxf(por, 1e-6f), 1.0f - 1e-6f);
    float sor = logf(por) - log1pf(-por);
    out_total[row] = alpha * smain + (1.0f - alpha) * sor;
  }
}

extern "C" void kernel_launch(void* const* d_in, const int* in_sizes, int n_in,
                              void* d_out, int out_size, void* d_ws,
                              size_t ws_size, hipStream_t stream) {
  const float* mu = (const float*)d_in[0];
  const float* logvar = (const float*)d_in[1];
  const float* minutes = (const float*)d_in[2];
  const float* mu_c = (const float*)d_in[3];
  const float* log_tau2 = (const float*)d_in[4];
  const float* log_prior = (const float*)d_in[5];
  const float* W1 = (const float*)d_in[6];
  const float* b1 = (const float*)d_in[7];
  const float* W2 = (const float*)d_in[8];
  const float* b2 = (const float*)d_in[9];
  const float* alpha_logits = (const float*)d_in[10];
  const float* attn_lambda_logit = (const float*)d_in[11];
  const float* decay_rate_log = (const float*)d_in[12];

  float* out = (float*)d_out;
  float* out_total = out;             // [256]
  float* out_s = out + B_DIM;        // [131072]
  float* out_a = out + B_DIM + NTOK; // [131072] — holds a_raw between kernels
  float* wsc = (float*)d_ws;
  float* ws_score = wsc + WS_SCORE;

  k_setup<<<128, 256, 0, stream>>>(W1, b1, W2, mu_c, log_tau2, log_prior, wsc);
  k_token<<<NTOK / TPB, 512, 0, stream>>>(mu, logvar, minutes, b2, wsc, out_s,
                                          ws_score, out_a);
  k_row<<<B_DIM, 256, 0, stream>>>(minutes, out_s, ws_score, out_a,
                                   alpha_logits, attn_lambda_logit,
                                   decay_rate_log, out_total);
}